// Round 4
// baseline (555.199 us; speedup 1.0000x reference)
//
#include <hip/hip_runtime.h>

// BoneLengthLoss: masked MSE over 32 bone lengths, B=524288, 37 kpts, fp32.
// ~485 MB input stream -> HBM floor ~77-91us.
//
// Mechanism matrix (all ~210-220us): shallow-glds (R1-R4), deep-glds (R5),
// shallow-reg (R7, scratch-proof, WRITE_SIZE~0). Little's-law back-solve:
// delivered 3.6 B/cyc/CU x 33K-cyc tile period ~= 118 KB = exactly one
// block-tile of loads -> we are OUTSTANDING-limited under full-GPU
// contention (queueing latency >> 900cy). Every tested cell lets per-wave
// outstanding drop to ~0 once per tile (or routes through glds).
// R8 (this): the untested cell -- TWO-deep register pipeline with plain
// loads. Named float4 locals x2 buffers (A/B, ~118 staging VGPRs, stays in
// registers per R7's verified pattern). At every moment >=17 loads/wave in
// flight; each ST_X waits on loads issued two compute+barrier phases ago.
// Single LDS buffer; raw s_barrier + lgkmcnt(0) only; vmcnt never drained.

#define NKPT   37
#define ROWF   111             // floats per pose row
#define TROWS  64              // rows per tile (= lane)
#define TF4    1776            // float4 per tile per array (64*111/4)
#define WF4    444             // float4 per wave slice (6*64 + 60)
#define TMB    2368            // mask bytes per tile
#define TMW    592             // mask words per tile
#define WMW    148             // mask words per wave (2*64 + 20)
#define BLOCK  256
#define WPB    4
#define GRID   512             // 2 blocks/CU * 256 CU; 8192/512 = 16 tiles exact

constexpr int J1[32] = {1,1,1,2,3,11,11,12,13,14,15,16,12,18,20,13,19,21,16,16,24,25,24,27,29,25,28,30,17,33,34,35};
constexpr int J2[32] = {2,3,4,5,6,12,13,14,14,15,16,17,18,20,22,19,21,23,24,25,26,26,27,29,31,28,30,32,33,34,35,36};

#define LGKM0() asm volatile("s_waitcnt lgkmcnt(0)" ::: "memory")
#define BAR()   __builtin_amdgcn_s_barrier()

// ws[0]=num(f32) ws[1]=den(u32) ws[2]=mask-layout flag ws[3]=done counter
__global__ void init_detect(const unsigned int* __restrict__ mw,
                            unsigned int* __restrict__ ws) {
    const int tid = threadIdx.x;
    if (tid < 4) ws[tid] = 0u;
    __syncthreads();
    unsigned int local = 0;
    for (int i = tid; i < 1024; i += BLOCK) local |= mw[i] & 0xFFFFFF00u;
    if (__any(local != 0) && (tid & 63) == 0) atomicOr(&ws[2], 1u);
}

// Merged lens+acc: pred and ref rows both live in LDS. All offsets
// compile-time; endpoint reads CSE'd by the compiler.
template <int G>
__device__ __forceinline__ void do_tile(const float* __restrict__ sp,
                                        const float* __restrict__ sq,
                                        const unsigned char* __restrict__ sm,
                                        float& num, unsigned int& den) {
#pragma unroll
    for (int k = 0; k < 8; ++k) {
        const int a = J1[G * 8 + k], b = J2[G * 8 + k];
        const int a3 = a * 3, b3 = b * 3;
        float pdx = sp[b3] - sp[a3];
        float pdy = sp[b3 + 1] - sp[a3 + 1];
        float pdz = sp[b3 + 2] - sp[a3 + 2];
        float qdx = sq[b3] - sq[a3];
        float qdy = sq[b3 + 1] - sq[a3 + 1];
        float qdz = sq[b3 + 2] - sq[a3 + 2];
        float pl = __builtin_amdgcn_sqrtf(pdx * pdx + pdy * pdy + pdz * pdz);
        float ql = __builtin_amdgcn_sqrtf(qdx * qdx + qdy * qdy + qdz * qdz);
        unsigned int v = (unsigned int)(sm[a] & sm[b]);
        float d = pl - ql;
        num += v ? d * d : 0.0f;
        den += v;
    }
}

#define COMPUTE() do { switch (wave) { \
    case 0: do_tile<0>(sp_row, sq_row, sm_row, num, den); break; \
    case 1: do_tile<1>(sp_row, sq_row, sm_row, num, den); break; \
    case 2: do_tile<2>(sp_row, sq_row, sm_row, num, den); break; \
    default: do_tile<3>(sp_row, sq_row, sm_row, num, den); break; } } while (0)

// Issue all 17 loads for tile (t) into buffer-suffixed named locals. All
// variables unconditionally defined (tail addresses clamped in-bounds;
// duplicate reads for tail-excess lanes; their stores are masked off).
#define LD(t, S) do { \
    const float4* pb = pred4 + (size_t)(t) * TF4 + wave * WF4; \
    const float4* qb = ref4  + (size_t)(t) * TF4 + wave * WF4; \
    const unsigned int* mb = mw + (size_t)(t) * TMW + wave * WMW; \
    p0##S = pb[lane];        q0##S = qb[lane]; \
    p1##S = pb[64  + lane];  q1##S = qb[64  + lane]; \
    p2##S = pb[128 + lane];  q2##S = qb[128 + lane]; \
    p3##S = pb[192 + lane];  q3##S = qb[192 + lane]; \
    p4##S = pb[256 + lane];  q4##S = qb[256 + lane]; \
    p5##S = pb[320 + lane];  q5##S = qb[320 + lane]; \
    p6##S = pb[384 + lane6]; q6##S = qb[384 + lane6]; \
    m0##S = mb[lane]; m1##S = mb[64 + lane]; m2##S = mb[128 + lanem]; \
} while (0)

// ds_write one buffer. Compiler inserts counted vmcnt waits for exactly the
// loads feeding these stores (issued two full phases earlier).
#define ST(S) do { \
    spw[lane]       = p0##S;  sqw[lane]       = q0##S; \
    spw[64  + lane] = p1##S;  sqw[64  + lane] = q1##S; \
    spw[128 + lane] = p2##S;  sqw[128 + lane] = q2##S; \
    spw[192 + lane] = p3##S;  sqw[192 + lane] = q3##S; \
    spw[256 + lane] = p4##S;  sqw[256 + lane] = q4##S; \
    spw[320 + lane] = p5##S;  sqw[320 + lane] = q5##S; \
    if (lane < 60) { spw[384 + lane] = p6##S; sqw[384 + lane] = q6##S; } \
    smw[lane] = m0##S; smw[64 + lane] = m1##S; \
    if (lane < 20) smw[128 + lane] = m2##S; \
} while (0)

__global__ __launch_bounds__(BLOCK, 2)
void bone_main(const float* __restrict__ pred, const float* __restrict__ ref,
               const void* __restrict__ mask, int B,
               unsigned int* __restrict__ ws, float* __restrict__ out) {
    __shared__ __align__(16) float4 s_pred[TF4];            // 28416 B
    __shared__ __align__(16) float4 s_ref[TF4];             // 28416 B
    __shared__ __align__(16) unsigned int s_maskw[TMW];     //  2368 B
    __shared__ float s_rn[WPB];
    __shared__ unsigned int s_rd[WPB];

    const int tid  = threadIdx.x;
    const int wave = tid >> 6;
    const int lane = tid & 63;                 // = row within the 64-row tile
    const int lane6 = (lane < 60) ? lane : 59; // clamped tail indices
    const int lanem = (lane < 20) ? lane : 19;

    const bool mask_bytes = (ws[2] != 0);
    const int ntiles = B / TROWS;              // 8192

    const float4* __restrict__ pred4 = (const float4*)pred;
    const float4* __restrict__ ref4  = (const float4*)ref;
    const unsigned int* __restrict__ mw = (const unsigned int*)mask;
    const int* __restrict__ mi = (const int*)mask;

    float4* spw = s_pred + wave * WF4;
    float4* sqw = s_ref  + wave * WF4;
    unsigned int* smw = s_maskw + wave * WMW;

    const float* sp_row = (const float*)s_pred + lane * ROWF;
    const float* sq_row = (const float*)s_ref  + lane * ROWF;
    const unsigned char* sm_row = (const unsigned char*)s_maskw + lane * NKPT;

    float num = 0.0f;
    unsigned int den = 0u;

    const int bid = blockIdx.x;
    const int ntb = (bid < ntiles) ? (ntiles - bid + GRID - 1) / GRID : 0;

    if (mask_bytes && ntb >= 2 && (ntb & 1) == 0) {
        // ---- two-deep register pipeline (named locals only) ----
        float4 p0A, p1A, p2A, p3A, p4A, p5A, p6A;
        float4 q0A, q1A, q2A, q3A, q4A, q5A, q6A;
        unsigned int m0A, m1A, m2A;
        float4 p0B, p1B, p2B, p3B, p4B, p5B, p6B;
        float4 q0B, q1B, q2B, q3B, q4B, q5B, q6B;
        unsigned int m0B, m1B, m2B;

        LD(bid, A);                              // T_0 in flight
        LD(bid + GRID, B);                       // T_1 in flight
        for (int j = 0; j < ntb; j += 2) {
            ST(A);                               // waits T_j loads; T_{j+1} still in flight
            { int tn = bid + (j + 2) * GRID;
              if (tn < ntiles) LD(tn, A); }      // T_{j+2} in flight
            LGKM0(); BAR();                      // LDS = T_j visible
            COMPUTE();
            LGKM0(); BAR();                      // all waves done reading

            ST(B);                               // waits T_{j+1}; T_{j+2} still in flight
            { int tn = bid + (j + 3) * GRID;
              if (tn < ntiles) LD(tn, B); }      // T_{j+3} in flight
            LGKM0(); BAR();                      // LDS = T_{j+1} visible
            COMPUTE();
            LGKM0(); BAR();
        }
    } else {
        // ---- fallback: fully drained, handles both mask layouts ----
        for (int t = bid; t < ntiles; t += GRID) {
            for (int i = tid; i < TF4; i += BLOCK) {
                s_pred[i] = pred4[(size_t)t * TF4 + i];
                s_ref[i]  = ref4[(size_t)t * TF4 + i];
            }
            if (mask_bytes) {
                for (int i = tid; i < TMW; i += BLOCK)
                    s_maskw[i] = mw[(size_t)t * TMW + i];
            } else {
                unsigned char* smb = (unsigned char*)s_maskw;
                const int* mb = mi + (size_t)t * TMB;
                for (int i = tid; i < TMB; i += BLOCK)
                    smb[i] = (unsigned char)mb[i];
            }
            __syncthreads();
            COMPUTE();
            __syncthreads();
        }
    }

    // ---- reduce: wave shuffle -> block partials -> one atomic per block ----
#pragma unroll
    for (int off = 32; off > 0; off >>= 1) {
        num += __shfl_down(num, off, 64);
        den += __shfl_down(den, off, 64);
    }
    if (lane == 0) { s_rn[wave] = num; s_rd[wave] = den; }
    __syncthreads();
    if (tid == 0) {
        float n = s_rn[0] + s_rn[1] + s_rn[2] + s_rn[3];
        unsigned int d = s_rd[0] + s_rd[1] + s_rd[2] + s_rd[3];
        atomicAdd((float*)&ws[0], n);
        atomicAdd(&ws[1], d);
        __threadfence();
        unsigned int prev = atomicAdd(&ws[3], 1u);
        if (prev == (unsigned int)(gridDim.x - 1)) {
            float fn = atomicAdd((float*)&ws[0], 0.0f);
            unsigned int fd = atomicAdd(&ws[1], 0u);
            out[0] = fn / (float)fd;
        }
    }
}

extern "C" void kernel_launch(void* const* d_in, const int* in_sizes, int n_in,
                              void* d_out, int out_size, void* d_ws, size_t ws_size,
                              hipStream_t stream) {
    const float* pred = (const float*)d_in[0];
    const float* ref  = (const float*)d_in[1];
    const void*  mask = d_in[2];
    const int n_mask  = in_sizes[2];           // 524288 * 37 elements
    const int B       = n_mask / NKPT;
    unsigned int* ws  = (unsigned int*)d_ws;

    init_detect<<<1, BLOCK, 0, stream>>>((const unsigned int*)mask, ws);
    bone_main<<<GRID, BLOCK, 0, stream>>>(pred, ref, mask, B, ws, (float*)d_out);
}